// Round 6
// baseline (217.301 us; speedup 1.0000x reference)
//
#include <hip/hip_runtime.h>
#include <hip/hip_bf16.h>

#define S   4096
#define DM  1024
#define DK  128

typedef __attribute__((ext_vector_type(8))) short short8;
typedef __attribute__((ext_vector_type(4))) float f32x4;

static __device__ __forceinline__ unsigned short f2bf(float f) {
    unsigned u = __builtin_bit_cast(unsigned, f);
    unsigned r = (u + 0x7FFFu + ((u >> 16) & 1u)) >> 16;
    return (unsigned short)r;
}

// ---------- W transpose: WtB[pid][col][k] = bf16(W[k][col]) ------------------
__global__ __launch_bounds__(256) void wtrans_kernel(
    const float* __restrict__ Wq, const float* __restrict__ Wk,
    const float* __restrict__ Wv, unsigned short* __restrict__ WtB)
{
    const int pid = blockIdx.z;
    const float* W = pid == 0 ? Wq : (pid == 1 ? Wk : Wv);
    unsigned short* T = WtB + (size_t)pid * DK * DM;
    const int k0 = blockIdx.x * 32, c0 = blockIdx.y * 32;
    __shared__ unsigned short tile[32][33];
    const int x = threadIdx.x & 31, y = threadIdx.x >> 5;   // 32 x 8
    #pragma unroll
    for (int i = 0; i < 32; i += 8)
        tile[y + i][x] = f2bf(W[(size_t)(k0 + y + i) * DK + c0 + x]);
    __syncthreads();
    #pragma unroll
    for (int i = 0; i < 32; i += 8)
        T[(size_t)(c0 + y + i) * DM + k0 + x] = tile[x][y + i];
}

// ---------- Projection: P = X @ W + b, bf16 out ------------------------------
// q-projection is pre-scaled by 1/sqrt(DK) (scores are linear in q), so the
// attention kernels skip the scale multiply.
#define PBK 64
__global__ __launch_bounds__(256) void proj_kernel(
    const float* __restrict__ q, const float* __restrict__ k, const float* __restrict__ v,
    const float* __restrict__ bq, const float* __restrict__ bk, const float* __restrict__ bv,
    const unsigned short* __restrict__ WtB,
    unsigned short* __restrict__ qp, unsigned short* __restrict__ kp,
    unsigned short* __restrict__ vpF)
{
    const int pid = blockIdx.y;
    const float* X    = pid == 0 ? q  : (pid == 1 ? k  : v);
    const float* bias = pid == 0 ? bq : (pid == 1 ? bk : bv);
    unsigned short* out = pid == 0 ? qp : (pid == 1 ? kp : vpF);
    const unsigned short* Wt = WtB + (size_t)pid * DK * DM;
    const float oscale = pid == 0 ? 0.08838834764831843f : 1.0f;

    const int rows0 = blockIdx.x * 32;
    const int tid  = threadIdx.x;
    const int lane = tid & 63;
    const int wave = tid >> 6;
    const int lw = lane & 15, lg = lane >> 4;
    const int wrow = (wave >> 1) * 16;      // 0 or 16
    const int wcol = (wave & 1) * 64;       // 0 or 64

    __shared__ unsigned short Xs[32][PBK];  // 4 KB, XOR-swizzled 16B granules

    f32x4 acc[4];
    #pragma unroll
    for (int i = 0; i < 4; i++) acc[i] = f32x4{0.f, 0.f, 0.f, 0.f};

    const int srow = tid >> 3;              // staging row (32 rows x 8 thr)
    const int sg   = tid & 7;               // staging granule
    const int sgs  = sg ^ (srow & 7);       // swizzled granule

    for (int k0 = 0; k0 < DM; k0 += PBK) {
        const float* src = X + (size_t)(rows0 + srow) * DM + k0 + sg * 8;
        float4 a = *reinterpret_cast<const float4*>(src);
        float4 b = *reinterpret_cast<const float4*>(src + 4);
        short8 xb;
        xb[0] = (short)f2bf(a.x); xb[1] = (short)f2bf(a.y);
        xb[2] = (short)f2bf(a.z); xb[3] = (short)f2bf(a.w);
        xb[4] = (short)f2bf(b.x); xb[5] = (short)f2bf(b.y);
        xb[6] = (short)f2bf(b.z); xb[7] = (short)f2bf(b.w);
        *reinterpret_cast<short8*>(&Xs[srow][sgs * 8]) = xb;
        __syncthreads();
        #pragma unroll
        for (int kk = 0; kk < 2; kk++) {
            const int g = (kk * 4 + lg) ^ (lw & 7);
            short8 af = *reinterpret_cast<const short8*>(&Xs[wrow + lw][g * 8]);
            #pragma unroll
            for (int f = 0; f < 4; f++) {
                const unsigned short* wp =
                    Wt + (size_t)(wcol + f * 16 + lw) * DM + k0 + kk * 32 + lg * 8;
                short8 bf = *reinterpret_cast<const short8*>(wp);
                acc[f] = __builtin_amdgcn_mfma_f32_16x16x32_bf16(af, bf, acc[f], 0, 0, 0);
            }
        }
        __syncthreads();
    }

    const int orow = rows0 + wrow + lg * 4;
    if (pid != 2) {
        #pragma unroll
        for (int f = 0; f < 4; f++) {
            int col = wcol + f * 16 + lw;
            float bb = bias[col];
            #pragma unroll
            for (int r = 0; r < 4; r++)
                out[(size_t)(orow + r) * DK + col] = f2bf((acc[f][r] + bb) * oscale);
        }
    } else {
        #pragma unroll
        for (int f = 0; f < 4; f++) {
            int col = wcol + f * 16 + lw;
            float bb = bias[col];
            #pragma unroll
            for (int r = 0; r < 4; r++) {
                int row = orow + r;
                out[(size_t)(row >> 5) * DK * 32 + (size_t)col * 32 + (row & 31)] =
                    f2bf(acc[f][r] + bb);
            }
        }
    }
}

// ---------- Attention phase 1: balanced split-K partials ---------------------
// Work-unit = (16-row q-tile i, 256-key block kb). One wave per unit.
// Dense unit index u = 8a(a+1) + r(a+1) + kb, a=i>>4, r=i&15.
// Writes unnormalized O (f32) + per-row (m, l).
__global__ __launch_bounds__(64) void attn_part_kernel(
    const unsigned short* __restrict__ qp,
    const unsigned short* __restrict__ kp,
    const unsigned short* __restrict__ vpF,
    float* __restrict__ part_O, float* __restrict__ part_ml)
{
    const int i  = blockIdx.y;               // q-tile
    const int kb = blockIdx.x;               // 256-key block
    const int nkb = (i + 16) >> 4;           // ceil((i+1)/16)
    if (kb >= nkb) return;
    const int a = i >> 4, rr = i & 15;
    const int u = 8 * a * (a + 1) + rr * (a + 1) + kb;

    const int lane = threadIdx.x;
    const int lw = lane & 15, lg = lane >> 4;
    const int q0 = i * 16;
    const int kstart = kb * 256;
    const int kend = min(kstart + 256, q0 + 16);
    const int ntl = (kend - kstart + 31) >> 5;

    __shared__ unsigned short Pl[16][32];

    short8 qf[4];
    {
        const unsigned short* qb = qp + (size_t)(q0 + lw) * DK + lg * 8;
        #pragma unroll
        for (int t = 0; t < 4; t++)
            qf[t] = *reinterpret_cast<const short8*>(qb + t * 32);
    }

    f32x4 oacc[8];
    #pragma unroll
    for (int i2 = 0; i2 < 8; i2++) oacc[i2] = f32x4{0.f, 0.f, 0.f, 0.f};
    float m[4]    = {-1e30f, -1e30f, -1e30f, -1e30f};
    float lsum[4] = {0.f, 0.f, 0.f, 0.f};

    for (int t = 0; t < ntl; ++t) {
        const int k0 = kstart + t * 32;
        f32x4 sc0 = f32x4{0.f, 0.f, 0.f, 0.f};
        f32x4 sc1 = f32x4{0.f, 0.f, 0.f, 0.f};
        {
            const unsigned short* kb0 = kp + (size_t)(k0 + lw) * DK + lg * 8;
            const unsigned short* kb1 = kb0 + 16 * DK;
            #pragma unroll
            for (int tt = 0; tt < 4; tt++) {
                short8 b0 = *reinterpret_cast<const short8*>(kb0 + tt * 32);
                short8 b1 = *reinterpret_cast<const short8*>(kb1 + tt * 32);
                sc0 = __builtin_amdgcn_mfma_f32_16x16x32_bf16(qf[tt], b0, sc0, 0, 0, 0);
                sc1 = __builtin_amdgcn_mfma_f32_16x16x32_bf16(qf[tt], b1, sc1, 0, 0, 0);
            }
        }
        float mx[4];
        #pragma unroll
        for (int r = 0; r < 4; r++) {
            int qg = q0 + lg * 4 + r;
            float s0 = sc0[r]; if (k0 + lw > qg)      s0 = -1e30f;
            float s1 = sc1[r]; if (k0 + 16 + lw > qg) s1 = -1e30f;
            sc0[r] = s0; sc1[r] = s1;
            mx[r] = fmaxf(s0, s1);
        }
        #pragma unroll
        for (int off = 1; off < 16; off <<= 1) {
            #pragma unroll
            for (int r = 0; r < 4; r++)
                mx[r] = fmaxf(mx[r], __shfl_xor(mx[r], off));
        }
        float corr[4], rs[4];
        #pragma unroll
        for (int r = 0; r < 4; r++) {
            float mn = fmaxf(m[r], mx[r]);
            corr[r] = __expf(m[r] - mn);
            m[r] = mn;
            float p0 = __expf(sc0[r] - mn);
            float p1 = __expf(sc1[r] - mn);
            rs[r] = p0 + p1;
            Pl[lg * 4 + r][lw]      = f2bf(p0);
            Pl[lg * 4 + r][16 + lw] = f2bf(p1);
        }
        #pragma unroll
        for (int off = 1; off < 16; off <<= 1) {
            #pragma unroll
            for (int r = 0; r < 4; r++)
                rs[r] += __shfl_xor(rs[r], off);
        }
        #pragma unroll
        for (int r = 0; r < 4; r++) lsum[r] = lsum[r] * corr[r] + rs[r];
        #pragma unroll
        for (int f = 0; f < 8; f++) {
            oacc[f][0] *= corr[0]; oacc[f][1] *= corr[1];
            oacc[f][2] *= corr[2]; oacc[f][3] *= corr[3];
        }
        asm volatile("s_waitcnt lgkmcnt(0)" ::: "memory");
        short8 pa = *reinterpret_cast<const short8*>(&Pl[lw][lg * 8]);
        const unsigned short* vb = vpF + (size_t)(k0 >> 5) * DK * 32 + lg * 8;
        #pragma unroll
        for (int f = 0; f < 8; f++) {
            short8 bf = *reinterpret_cast<const short8*>(vb + (size_t)(f * 16 + lw) * 32);
            oacc[f] = __builtin_amdgcn_mfma_f32_16x16x32_bf16(pa, bf, oacc[f], 0, 0, 0);
        }
    }

    // store partials
    float* po = part_O + (size_t)u * 2048;
    #pragma unroll
    for (int f = 0; f < 8; f++) {
        int col = f * 16 + lw;
        #pragma unroll
        for (int r = 0; r < 4; r++)
            po[(lg * 4 + r) * DK + col] = oacc[f][r];
    }
    if (lw == 0) {
        #pragma unroll
        for (int r = 0; r < 4; r++) {
            part_ml[(size_t)u * 32 + lg * 4 + r]      = m[r];
            part_ml[(size_t)u * 32 + 16 + lg * 4 + r] = lsum[r];
        }
    }
}

// ---------- Attention phase 2: LSE-weighted combine --------------------------
__global__ __launch_bounds__(128) void attn_comb_kernel(
    const float* __restrict__ part_O, const float* __restrict__ part_ml,
    float* __restrict__ out)
{
    const int i = blockIdx.x;
    const int nkb = (i + 16) >> 4;
    const int a = i >> 4, rr = i & 15;
    const int u0 = 8 * a * (a + 1) + rr * (a + 1);
    const int tid = threadIdx.x;

    __shared__ float wgt[16][16];   // [unit][row]
    __shared__ float invd[16];

    if (tid < 16) {
        float M = -1e30f;
        for (int u = 0; u < nkb; u++)
            M = fmaxf(M, part_ml[(size_t)(u0 + u) * 32 + tid]);
        float d = 0.f;
        for (int u = 0; u < nkb; u++) {
            float g = __expf(part_ml[(size_t)(u0 + u) * 32 + tid] - M);
            wgt[u][tid] = g;
            d += g * part_ml[(size_t)(u0 + u) * 32 + 16 + tid];
        }
        invd[tid] = 1.0f / d;
    }
    __syncthreads();

    #pragma unroll
    for (int j = 0; j < 16; j++) {
        int e = tid + 128 * j;              // 0..2047
        int r = e >> 7;
        float acc = 0.f;
        for (int u = 0; u < nkb; u++)
            acc += wgt[u][r] * part_O[(size_t)(u0 + u) * 2048 + e];
        out[(size_t)i * 2048 + e] = acc * invd[r];
    }
}

// ---------- Fallback: single-kernel split-K attn (qp pre-scaled) -------------
__global__ __launch_bounds__(512) void attn_fallback_kernel(
    const unsigned short* __restrict__ qp,
    const unsigned short* __restrict__ kp,
    const unsigned short* __restrict__ vpF,
    float* __restrict__ out)
{
    const int tid  = threadIdx.x;
    const int lane = tid & 63;
    const int wid  = tid >> 6;
    const int q0   = blockIdx.x * 16;
    const int lw = lane & 15, lg = lane >> 4;

    __shared__ unsigned short Pl[8][16][32];
    __shared__ float Ols[8][16][132];
    __shared__ float mls[8][16], lls[8][16];
    __shared__ float wgt[8][16], invd[16];

    short8 qf[4];
    {
        const unsigned short* qb = qp + (size_t)(q0 + lw) * DK + lg * 8;
        #pragma unroll
        for (int t = 0; t < 4; t++)
            qf[t] = *reinterpret_cast<const short8*>(qb + t * 32);
    }
    f32x4 oacc[8];
    #pragma unroll
    for (int i = 0; i < 8; i++) oacc[i] = f32x4{0.f, 0.f, 0.f, 0.f};
    float m[4]    = {-1e30f, -1e30f, -1e30f, -1e30f};
    float lsum[4] = {0.f, 0.f, 0.f, 0.f};
    const int nt = (q0 + 47) >> 5;

    for (int t = wid; t < nt; t += 8) {
        const int k0 = t * 32;
        f32x4 sc0 = f32x4{0.f, 0.f, 0.f, 0.f};
        f32x4 sc1 = f32x4{0.f, 0.f, 0.f, 0.f};
        {
            const unsigned short* kb0 = kp + (size_t)(k0 + lw) * DK + lg * 8;
            const unsigned short* kb1 = kb0 + 16 * DK;
            #pragma unroll
            for (int tt = 0; tt < 4; tt++) {
                short8 b0 = *reinterpret_cast<const short8*>(kb0 + tt * 32);
                short8 b1 = *reinterpret_cast<const short8*>(kb1 + tt * 32);
                sc0 = __builtin_amdgcn_mfma_f32_16x16x32_bf16(qf[tt], b0, sc0, 0, 0, 0);
                sc1 = __builtin_amdgcn_mfma_f32_16x16x32_bf16(qf[tt], b1, sc1, 0, 0, 0);
            }
        }
        float mx[4];
        #pragma unroll
        for (int r = 0; r < 4; r++) {
            int qg = q0 + lg * 4 + r;
            float s0 = sc0[r]; if (k0 + lw > qg)      s0 = -1e30f;
            float s1 = sc1[r]; if (k0 + 16 + lw > qg) s1 = -1e30f;
            sc0[r] = s0; sc1[r] = s1;
            mx[r] = fmaxf(s0, s1);
        }
        #pragma unroll
        for (int off = 1; off < 16; off <<= 1) {
            #pragma unroll
            for (int r = 0; r < 4; r++)
                mx[r] = fmaxf(mx[r], __shfl_xor(mx[r], off));
        }
        float corr[4], rs[4];
        #pragma unroll
        for (int r = 0; r < 4; r++) {
            float mn = fmaxf(m[r], mx[r]);
            corr[r] = __expf(m[r] - mn);
            m[r] = mn;
            float p0 = __expf(sc0[r] - mn);
            float p1 = __expf(sc1[r] - mn);
            rs[r] = p0 + p1;
            Pl[wid][lg * 4 + r][lw]      = f2bf(p0);
            Pl[wid][lg * 4 + r][16 + lw] = f2bf(p1);
        }
        #pragma unroll
        for (int off = 1; off < 16; off <<= 1) {
            #pragma unroll
            for (int r = 0; r < 4; r++)
                rs[r] += __shfl_xor(rs[r], off);
        }
        #pragma unroll
        for (int r = 0; r < 4; r++) lsum[r] = lsum[r] * corr[r] + rs[r];
        #pragma unroll
        for (int f = 0; f < 8; f++) {
            oacc[f][0] *= corr[0]; oacc[f][1] *= corr[1];
            oacc[f][2] *= corr[2]; oacc[f][3] *= corr[3];
        }
        asm volatile("s_waitcnt lgkmcnt(0)" ::: "memory");
        short8 pa = *reinterpret_cast<const short8*>(&Pl[wid][lw][lg * 8]);
        const unsigned short* vb = vpF + (size_t)(k0 >> 5) * DK * 32 + lg * 8;
        #pragma unroll
        for (int f = 0; f < 8; f++) {
            short8 bf = *reinterpret_cast<const short8*>(vb + (size_t)(f * 16 + lw) * 32);
            oacc[f] = __builtin_amdgcn_mfma_f32_16x16x32_bf16(pa, bf, oacc[f], 0, 0, 0);
        }
    }
    #pragma unroll
    for (int f = 0; f < 8; f++) {
        int col = f * 16 + lw;
        #pragma unroll
        for (int r = 0; r < 4; r++)
            Ols[wid][lg * 4 + r][col] = oacc[f][r];
    }
    if (lw == 0) {
        #pragma unroll
        for (int r = 0; r < 4; r++) {
            mls[wid][lg * 4 + r] = m[r];
            lls[wid][lg * 4 + r] = lsum[r];
        }
    }
    __syncthreads();
    if (tid < 16) {
        float M = mls[0][tid];
        #pragma unroll
        for (int w2 = 1; w2 < 8; w2++) M = fmaxf(M, mls[w2][tid]);
        float d = 0.f;
        #pragma unroll
        for (int w2 = 0; w2 < 8; w2++) {
            float g = __expf(mls[w2][tid] - M);
            wgt[w2][tid] = g;
            d += g * lls[w2][tid];
        }
        invd[tid] = 1.0f / d;
    }
    __syncthreads();
    #pragma unroll
    for (int j = 0; j < 4; j++) {
        int e = tid + 512 * j;
        int r = e >> 7, c = e & 127;
        float num = 0.f;
        #pragma unroll
        for (int w2 = 0; w2 < 8; w2++) num += wgt[w2][r] * Ols[w2][r][c];
        out[(size_t)(q0 + r) * DK + c] = num * invd[r];
    }
}

extern "C" void kernel_launch(void* const* d_in, const int* in_sizes, int n_in,
                              void* d_out, int out_size, void* d_ws, size_t ws_size,
                              hipStream_t stream) {
    const float* q  = (const float*)d_in[0];
    const float* k  = (const float*)d_in[1];
    const float* v  = (const float*)d_in[2];
    const float* Wq = (const float*)d_in[3];
    const float* bq = (const float*)d_in[4];
    const float* Wk = (const float*)d_in[5];
    const float* bk = (const float*)d_in[6];
    const float* Wv = (const float*)d_in[7];
    const float* bv = (const float*)d_in[8];

    unsigned short* qp  = (unsigned short*)d_ws;
    unsigned short* kp  = qp + (size_t)S * DK;
    unsigned short* vpF = kp + (size_t)S * DK;
    unsigned short* WtB = vpF + (size_t)S * DK;          // [3][128][1024] bf16
    float* part_O  = (float*)(WtB + (size_t)3 * DK * DM); // [2176][16][128] f32
    float* part_ml = part_O + (size_t)2176 * 2048;        // [2176][32] f32

    const size_t ws_need = ((size_t)3 * S * DK + (size_t)3 * DK * DM) * 2 +
                           ((size_t)2176 * 2048 + (size_t)2176 * 32) * 4;

    dim3 gt(DM / 32, DK / 32, 3);
    wtrans_kernel<<<gt, 256, 0, stream>>>(Wq, Wk, Wv, WtB);

    dim3 gp(S / 32, 3);
    proj_kernel<<<gp, 256, 0, stream>>>(q, k, v, bq, bk, bv, WtB, qp, kp, vpF);

    if (ws_size >= ws_need) {
        dim3 ga(16, S / 16);
        attn_part_kernel<<<ga, 64, 0, stream>>>(qp, kp, vpF, part_O, part_ml);
        attn_comb_kernel<<<S / 16, 128, 0, stream>>>(part_O, part_ml, (float*)d_out);
    } else {
        attn_fallback_kernel<<<S / 16, 512, 0, stream>>>(qp, kp, vpF, (float*)d_out);
    }
}

// Round 7
// 200.517 us; speedup vs baseline: 1.0837x; 1.0837x over previous
//
#include <hip/hip_runtime.h>
#include <hip/hip_bf16.h>
#include <math.h>

#define S   4096
#define DM  1024
#define DK  128

typedef __attribute__((ext_vector_type(8))) short short8;
typedef __attribute__((ext_vector_type(4))) float f32x4;

static __device__ __forceinline__ unsigned short f2bf(float f) {
    unsigned u = __builtin_bit_cast(unsigned, f);
    unsigned r = (u + 0x7FFFu + ((u >> 16) & 1u)) >> 16;
    return (unsigned short)r;
}

// ---------- W transpose: WtB[pid][col][k] = bf16(W[k][col]) ------------------
__global__ __launch_bounds__(256) void wtrans_kernel(
    const float* __restrict__ Wq, const float* __restrict__ Wk,
    const float* __restrict__ Wv, unsigned short* __restrict__ WtB)
{
    const int pid = blockIdx.z;
    const float* W = pid == 0 ? Wq : (pid == 1 ? Wk : Wv);
    unsigned short* T = WtB + (size_t)pid * DK * DM;
    const int k0 = blockIdx.x * 32, c0 = blockIdx.y * 32;
    __shared__ unsigned short tile[32][33];
    const int x = threadIdx.x & 31, y = threadIdx.x >> 5;   // 32 x 8
    #pragma unroll
    for (int i = 0; i < 32; i += 8)
        tile[y + i][x] = f2bf(W[(size_t)(k0 + y + i) * DK + c0 + x]);
    __syncthreads();
    #pragma unroll
    for (int i = 0; i < 32; i += 8)
        T[(size_t)(c0 + y + i) * DM + k0 + x] = tile[x][y + i];
}

// ---------- Projection: P = X @ W + b, bf16 out ------------------------------
// q-projection pre-scaled by 1/sqrt(DK); attention kernels skip the multiply.
#define PBK 64
__global__ __launch_bounds__(256) void proj_kernel(
    const float* __restrict__ q, const float* __restrict__ k, const float* __restrict__ v,
    const float* __restrict__ bq, const float* __restrict__ bk, const float* __restrict__ bv,
    const unsigned short* __restrict__ WtB,
    unsigned short* __restrict__ qp, unsigned short* __restrict__ kp,
    unsigned short* __restrict__ vpF)
{
    const int pid = blockIdx.y;
    const float* X    = pid == 0 ? q  : (pid == 1 ? k  : v);
    const float* bias = pid == 0 ? bq : (pid == 1 ? bk : bv);
    unsigned short* out = pid == 0 ? qp : (pid == 1 ? kp : vpF);
    const unsigned short* Wt = WtB + (size_t)pid * DK * DM;
    const float oscale = pid == 0 ? 0.08838834764831843f : 1.0f;

    const int rows0 = blockIdx.x * 32;
    const int tid  = threadIdx.x;
    const int lane = tid & 63;
    const int wave = tid >> 6;
    const int lw = lane & 15, lg = lane >> 4;
    const int wrow = (wave >> 1) * 16;      // 0 or 16
    const int wcol = (wave & 1) * 64;       // 0 or 64

    __shared__ unsigned short Xs[32][PBK];  // 4 KB, XOR-swizzled 16B granules

    f32x4 acc[4];
    #pragma unroll
    for (int i = 0; i < 4; i++) acc[i] = f32x4{0.f, 0.f, 0.f, 0.f};

    const int srow = tid >> 3;              // staging row (32 rows x 8 thr)
    const int sg   = tid & 7;               // staging granule
    const int sgs  = sg ^ (srow & 7);       // swizzled granule

    for (int k0 = 0; k0 < DM; k0 += PBK) {
        const float* src = X + (size_t)(rows0 + srow) * DM + k0 + sg * 8;
        float4 a = *reinterpret_cast<const float4*>(src);
        float4 b = *reinterpret_cast<const float4*>(src + 4);
        short8 xb;
        xb[0] = (short)f2bf(a.x); xb[1] = (short)f2bf(a.y);
        xb[2] = (short)f2bf(a.z); xb[3] = (short)f2bf(a.w);
        xb[4] = (short)f2bf(b.x); xb[5] = (short)f2bf(b.y);
        xb[6] = (short)f2bf(b.z); xb[7] = (short)f2bf(b.w);
        *reinterpret_cast<short8*>(&Xs[srow][sgs * 8]) = xb;
        __syncthreads();
        #pragma unroll
        for (int kk = 0; kk < 2; kk++) {
            const int g = (kk * 4 + lg) ^ (lw & 7);
            short8 af = *reinterpret_cast<const short8*>(&Xs[wrow + lw][g * 8]);
            #pragma unroll
            for (int f = 0; f < 4; f++) {
                const unsigned short* wp =
                    Wt + (size_t)(wcol + f * 16 + lw) * DM + k0 + kk * 32 + lg * 8;
                short8 bf = *reinterpret_cast<const short8*>(wp);
                acc[f] = __builtin_amdgcn_mfma_f32_16x16x32_bf16(af, bf, acc[f], 0, 0, 0);
            }
        }
        __syncthreads();
    }

    const int orow = rows0 + wrow + lg * 4;
    if (pid != 2) {
        #pragma unroll
        for (int f = 0; f < 4; f++) {
            int col = wcol + f * 16 + lw;
            float bb = bias[col];
            #pragma unroll
            for (int r = 0; r < 4; r++)
                out[(size_t)(orow + r) * DK + col] = f2bf((acc[f][r] + bb) * oscale);
        }
    } else {
        #pragma unroll
        for (int f = 0; f < 4; f++) {
            int col = wcol + f * 16 + lw;
            float bb = bias[col];
            #pragma unroll
            for (int r = 0; r < 4; r++) {
                int row = orow + r;
                out[(size_t)(row >> 5) * DK * 32 + (size_t)col * 32 + (row & 31)] =
                    f2bf(acc[f][r] + bb);
            }
        }
    }
}

// ---------- Attention phase 1: balanced split-K partials ---------------------
// Dense 1-D grid of 2176 units; unit u -> (q-tile i, 256-key block kb) via
// closed-form decode of u = 8a(a+1) + rr(a+1) + kb (a=i>>4, rr=i&15).
// 64-key inner tiles: 16 K-frag loads batched, both V slots prefetched during
// QK/softmax, causal mask only on the (wave-uniform) diagonal block.
__global__ __launch_bounds__(64, 2) void attn_part_kernel(
    const unsigned short* __restrict__ qp,
    const unsigned short* __restrict__ kp,
    const unsigned short* __restrict__ vpF,
    float* __restrict__ part_O, float* __restrict__ part_ml)
{
    const int u = blockIdx.x;
    int a = (int)(0.25f * (sqrtf(4.0f + 2.0f * (float)u) - 2.0f));
    while (8 * (a + 1) * (a + 2) <= u) ++a;
    while (8 * a * (a + 1) > u) --a;
    const int rem = u - 8 * a * (a + 1);
    const int rr2 = rem / (a + 1);
    const int kb = rem - rr2 * (a + 1);
    const int i  = a * 16 + rr2;

    const int lane = threadIdx.x;
    const int lw = lane & 15, lg = lane >> 4;
    const int q0 = i * 16;
    const int kstart = kb * 256;
    const int kend = min(kstart + 256, q0 + 16);
    const int nt = (kend - kstart + 63) >> 6;   // 64-key tiles
    const bool diag = (kb == a);

    __shared__ unsigned short Pl[16][72];   // +16B pad: ~2-way on b128 reads

    short8 qf[4];
    {
        const unsigned short* qb = qp + (size_t)(q0 + lw) * DK + lg * 8;
        #pragma unroll
        for (int t = 0; t < 4; t++)
            qf[t] = *reinterpret_cast<const short8*>(qb + t * 32);
    }

    f32x4 oacc[8];
    #pragma unroll
    for (int f = 0; f < 8; f++) oacc[f] = f32x4{0.f, 0.f, 0.f, 0.f};
    float m[4]    = {-1e30f, -1e30f, -1e30f, -1e30f};
    float lsum[4] = {0.f, 0.f, 0.f, 0.f};

    for (int t = 0; t < nt; ++t) {
        const int k0 = kstart + t * 64;

        // ---- QK^T over 64 keys: 16 batched K-frag loads, 4 indep MFMA chains
        short8 kf[4][4];   // [col-tile][k-chunk]
        const unsigned short* kbase = kp + (size_t)(k0 + lw) * DK + lg * 8;
        #pragma unroll
        for (int tt = 0; tt < 4; tt++)
            #pragma unroll
            for (int c = 0; c < 4; c++)
                kf[c][tt] = *reinterpret_cast<const short8*>(
                    kbase + (size_t)c * 16 * DK + tt * 32);
        f32x4 sc[4];
        #pragma unroll
        for (int c = 0; c < 4; c++) sc[c] = f32x4{0.f, 0.f, 0.f, 0.f};
        #pragma unroll
        for (int tt = 0; tt < 4; tt++)
            #pragma unroll
            for (int c = 0; c < 4; c++)
                sc[c] = __builtin_amdgcn_mfma_f32_16x16x32_bf16(qf[tt], kf[c][tt], sc[c], 0, 0, 0);

        // ---- V prefetch (both 32-key slots) — latency hides under softmax
        short8 vf[2][8];
        const unsigned short* vb = vpF + (size_t)(k0 >> 5) * DK * 32 + lg * 8;
        #pragma unroll
        for (int s = 0; s < 2; s++)
            #pragma unroll
            for (int f = 0; f < 8; f++)
                vf[s][f] = *reinterpret_cast<const short8*>(
                    vb + (size_t)s * DK * 32 + (size_t)(f * 16 + lw) * 32);

        // ---- causal mask: only the diagonal block (wave-uniform branch)
        if (diag) {
            #pragma unroll
            for (int c = 0; c < 4; c++) {
                int col = k0 + c * 16 + lw;
                #pragma unroll
                for (int r = 0; r < 4; r++)
                    if (col > q0 + lg * 4 + r) sc[c][r] = -1e30f;
            }
        }

        // ---- online softmax over 64 keys
        float mx[4], corr[4], rs[4];
        #pragma unroll
        for (int r = 0; r < 4; r++)
            mx[r] = fmaxf(fmaxf(sc[0][r], sc[1][r]), fmaxf(sc[2][r], sc[3][r]));
        #pragma unroll
        for (int off = 1; off < 16; off <<= 1) {
            #pragma unroll
            for (int r = 0; r < 4; r++)
                mx[r] = fmaxf(mx[r], __shfl_xor(mx[r], off));
        }
        #pragma unroll
        for (int r = 0; r < 4; r++) {
            float mn = fmaxf(m[r], mx[r]);
            corr[r] = __expf(m[r] - mn);
            m[r] = mn;
            float p0 = __expf(sc[0][r] - mn);
            float p1 = __expf(sc[1][r] - mn);
            float p2 = __expf(sc[2][r] - mn);
            float p3 = __expf(sc[3][r] - mn);
            rs[r] = (p0 + p1) + (p2 + p3);
            int row = lg * 4 + r;
            Pl[row][lw]      = f2bf(p0);
            Pl[row][16 + lw] = f2bf(p1);
            Pl[row][32 + lw] = f2bf(p2);
            Pl[row][48 + lw] = f2bf(p3);
        }
        #pragma unroll
        for (int off = 1; off < 16; off <<= 1) {
            #pragma unroll
            for (int r = 0; r < 4; r++)
                rs[r] += __shfl_xor(rs[r], off);
        }
        #pragma unroll
        for (int r = 0; r < 4; r++) lsum[r] = lsum[r] * corr[r] + rs[r];
        #pragma unroll
        for (int f = 0; f < 8; f++) {
            oacc[f][0] *= corr[0]; oacc[f][1] *= corr[1];
            oacc[f][2] *= corr[2]; oacc[f][3] *= corr[3];
        }

        // wave-local LDS fence: P writes -> P reads
        asm volatile("s_waitcnt lgkmcnt(0)" ::: "memory");

        // ---- PV over both 32-key slots (V already in registers)
        #pragma unroll
        for (int s = 0; s < 2; s++) {
            short8 pa = *reinterpret_cast<const short8*>(&Pl[lw][s * 32 + lg * 8]);
            #pragma unroll
            for (int f = 0; f < 8; f++)
                oacc[f] = __builtin_amdgcn_mfma_f32_16x16x32_bf16(pa, vf[s][f], oacc[f], 0, 0, 0);
        }
    }

    // ---- store partials
    float* po = part_O + (size_t)u * 2048;
    #pragma unroll
    for (int f = 0; f < 8; f++) {
        int col = f * 16 + lw;
        #pragma unroll
        for (int r = 0; r < 4; r++)
            po[(lg * 4 + r) * DK + col] = oacc[f][r];
    }
    if (lw == 0) {
        #pragma unroll
        for (int r = 0; r < 4; r++) {
            part_ml[(size_t)u * 32 + lg * 4 + r]      = m[r];
            part_ml[(size_t)u * 32 + 16 + lg * 4 + r] = lsum[r];
        }
    }
}

// ---------- Attention phase 2: LSE-weighted combine --------------------------
__global__ __launch_bounds__(128) void attn_comb_kernel(
    const float* __restrict__ part_O, const float* __restrict__ part_ml,
    float* __restrict__ out)
{
    const int i = blockIdx.x;
    const int nkb = (i + 16) >> 4;
    const int a = i >> 4, rr = i & 15;
    const int u0 = 8 * a * (a + 1) + rr * (a + 1);
    const int tid = threadIdx.x;

    __shared__ float wgt[16][16];   // [unit][row]
    __shared__ float invd[16];

    if (tid < 16) {
        float M = -1e30f;
        for (int u = 0; u < nkb; u++)
            M = fmaxf(M, part_ml[(size_t)(u0 + u) * 32 + tid]);
        float d = 0.f;
        for (int u = 0; u < nkb; u++) {
            float g = __expf(part_ml[(size_t)(u0 + u) * 32 + tid] - M);
            wgt[u][tid] = g;
            d += g * part_ml[(size_t)(u0 + u) * 32 + 16 + tid];
        }
        invd[tid] = 1.0f / d;
    }
    __syncthreads();

    #pragma unroll
    for (int j = 0; j < 16; j++) {
        int e = tid + 128 * j;              // 0..2047
        int r = e >> 7;
        float acc = 0.f;
        for (int u = 0; u < nkb; u++)
            acc += wgt[u][r] * part_O[(size_t)(u0 + u) * 2048 + e];
        out[(size_t)i * 2048 + e] = acc * invd[r];
    }
}

// ---------- Fallback: single-kernel split-K attn (qp pre-scaled) -------------
__global__ __launch_bounds__(512) void attn_fallback_kernel(
    const unsigned short* __restrict__ qp,
    const unsigned short* __restrict__ kp,
    const unsigned short* __restrict__ vpF,
    float* __restrict__ out)
{
    const int tid  = threadIdx.x;
    const int lane = tid & 63;
    const int wid  = tid >> 6;
    const int q0   = blockIdx.x * 16;
    const int lw = lane & 15, lg = lane >> 4;

    __shared__ unsigned short Pl[8][16][32];
    __shared__ float Ols[8][16][132];
    __shared__ float mls[8][16], lls[8][16];
    __shared__ float wgt[8][16], invd[16];

    short8 qf[4];
    {
        const unsigned short* qb = qp + (size_t)(q0 + lw) * DK + lg * 8;
        #pragma unroll
        for (int t = 0; t < 4; t++)
            qf[t] = *reinterpret_cast<const short8*>(qb + t * 32);
    }
    f32x4 oacc[8];
    #pragma unroll
    for (int i = 0; i < 8; i++) oacc[i] = f32x4{0.f, 0.f, 0.f, 0.f};
    float m[4]    = {-1e30f, -1e30f, -1e30f, -1e30f};
    float lsum[4] = {0.f, 0.f, 0.f, 0.f};
    const int nt = (q0 + 47) >> 5;

    for (int t = wid; t < nt; t += 8) {
        const int k0 = t * 32;
        f32x4 sc0 = f32x4{0.f, 0.f, 0.f, 0.f};
        f32x4 sc1 = f32x4{0.f, 0.f, 0.f, 0.f};
        {
            const unsigned short* kb0 = kp + (size_t)(k0 + lw) * DK + lg * 8;
            const unsigned short* kb1 = kb0 + 16 * DK;
            #pragma unroll
            for (int tt = 0; tt < 4; tt++) {
                short8 b0 = *reinterpret_cast<const short8*>(kb0 + tt * 32);
                short8 b1 = *reinterpret_cast<const short8*>(kb1 + tt * 32);
                sc0 = __builtin_amdgcn_mfma_f32_16x16x32_bf16(qf[tt], b0, sc0, 0, 0, 0);
                sc1 = __builtin_amdgcn_mfma_f32_16x16x32_bf16(qf[tt], b1, sc1, 0, 0, 0);
            }
        }
        float mx[4];
        #pragma unroll
        for (int r = 0; r < 4; r++) {
            int qg = q0 + lg * 4 + r;
            float s0 = sc0[r]; if (k0 + lw > qg)      s0 = -1e30f;
            float s1 = sc1[r]; if (k0 + 16 + lw > qg) s1 = -1e30f;
            sc0[r] = s0; sc1[r] = s1;
            mx[r] = fmaxf(s0, s1);
        }
        #pragma unroll
        for (int off = 1; off < 16; off <<= 1) {
            #pragma unroll
            for (int r = 0; r < 4; r++)
                mx[r] = fmaxf(mx[r], __shfl_xor(mx[r], off));
        }
        float corr[4], rs[4];
        #pragma unroll
        for (int r = 0; r < 4; r++) {
            float mn = fmaxf(m[r], mx[r]);
            corr[r] = __expf(m[r] - mn);
            m[r] = mn;
            float p0 = __expf(sc0[r] - mn);
            float p1 = __expf(sc1[r] - mn);
            rs[r] = p0 + p1;
            Pl[wid][lg * 4 + r][lw]      = f2bf(p0);
            Pl[wid][lg * 4 + r][16 + lw] = f2bf(p1);
        }
        #pragma unroll
        for (int off = 1; off < 16; off <<= 1) {
            #pragma unroll
            for (int r = 0; r < 4; r++)
                rs[r] += __shfl_xor(rs[r], off);
        }
        #pragma unroll
        for (int r = 0; r < 4; r++) lsum[r] = lsum[r] * corr[r] + rs[r];
        #pragma unroll
        for (int f = 0; f < 8; f++) {
            oacc[f][0] *= corr[0]; oacc[f][1] *= corr[1];
            oacc[f][2] *= corr[2]; oacc[f][3] *= corr[3];
        }
        asm volatile("s_waitcnt lgkmcnt(0)" ::: "memory");
        short8 pa = *reinterpret_cast<const short8*>(&Pl[wid][lw][lg * 8]);
        const unsigned short* vb = vpF + (size_t)(k0 >> 5) * DK * 32 + lg * 8;
        #pragma unroll
        for (int f = 0; f < 8; f++) {
            short8 bf = *reinterpret_cast<const short8*>(vb + (size_t)(f * 16 + lw) * 32);
            oacc[f] = __builtin_amdgcn_mfma_f32_16x16x32_bf16(pa, bf, oacc[f], 0, 0, 0);
        }
    }
    #pragma unroll
    for (int f = 0; f < 8; f++) {
        int col = f * 16 + lw;
        #pragma unroll
        for (int r = 0; r < 4; r++)
            Ols[wid][lg * 4 + r][col] = oacc[f][r];
    }
    if (lw == 0) {
        #pragma unroll
        for (int r = 0; r < 4; r++) {
            mls[wid][lg * 4 + r] = m[r];
            lls[wid][lg * 4 + r] = lsum[r];
        }
    }
    __syncthreads();
    if (tid < 16) {
        float M = mls[0][tid];
        #pragma unroll
        for (int w2 = 1; w2 < 8; w2++) M = fmaxf(M, mls[w2][tid]);
        float d = 0.f;
        #pragma unroll
        for (int w2 = 0; w2 < 8; w2++) {
            float g = __expf(mls[w2][tid] - M);
            wgt[w2][tid] = g;
            d += g * lls[w2][tid];
        }
        invd[tid] = 1.0f / d;
    }
    __syncthreads();
    #pragma unroll
    for (int j = 0; j < 4; j++) {
        int e = tid + 512 * j;
        int r = e >> 7, c = e & 127;
        float num = 0.f;
        #pragma unroll
        for (int w2 = 0; w2 < 8; w2++) num += wgt[w2][r] * Ols[w2][r][c];
        out[(size_t)(q0 + r) * DK + c] = num * invd[r];
    }
}

extern "C" void kernel_launch(void* const* d_in, const int* in_sizes, int n_in,
                              void* d_out, int out_size, void* d_ws, size_t ws_size,
                              hipStream_t stream) {
    const float* q  = (const float*)d_in[0];
    const float* k  = (const float*)d_in[1];
    const float* v  = (const float*)d_in[2];
    const float* Wq = (const float*)d_in[3];
    const float* bq = (const float*)d_in[4];
    const float* Wk = (const float*)d_in[5];
    const float* bk = (const float*)d_in[6];
    const float* Wv = (const float*)d_in[7];
    const float* bv = (const float*)d_in[8];

    unsigned short* qp  = (unsigned short*)d_ws;
    unsigned short* kp  = qp + (size_t)S * DK;
    unsigned short* vpF = kp + (size_t)S * DK;
    unsigned short* WtB = vpF + (size_t)S * DK;          // [3][128][1024] bf16
    float* part_O  = (float*)(WtB + (size_t)3 * DK * DM); // [2176][16][128] f32
    float* part_ml = part_O + (size_t)2176 * 2048;        // [2176][32] f32

    const size_t ws_need = ((size_t)3 * S * DK + (size_t)3 * DK * DM) * 2 +
                           ((size_t)2176 * 2048 + (size_t)2176 * 32) * 4;

    dim3 gt(DM / 32, DK / 32, 3);
    wtrans_kernel<<<gt, 256, 0, stream>>>(Wq, Wk, Wv, WtB);

    dim3 gp(S / 32, 3);
    proj_kernel<<<gp, 256, 0, stream>>>(q, k, v, bq, bk, bv, WtB, qp, kp, vpF);

    if (ws_size >= ws_need) {
        attn_part_kernel<<<2176, 64, 0, stream>>>(qp, kp, vpF, part_O, part_ml);
        attn_comb_kernel<<<S / 16, 128, 0, stream>>>(part_O, part_ml, (float*)d_out);
    } else {
        attn_fallback_kernel<<<S / 16, 512, 0, stream>>>(qp, kp, vpF, (float*)d_out);
    }
}

// Round 8
// 191.027 us; speedup vs baseline: 1.1375x; 1.0497x over previous
//
#include <hip/hip_runtime.h>
#include <hip/hip_bf16.h>
#include <math.h>

#define S   4096
#define DM  1024
#define DK  128

typedef __attribute__((ext_vector_type(8))) short short8;
typedef __attribute__((ext_vector_type(4))) float f32x4;

static __device__ __forceinline__ unsigned short f2bf(float f) {
    unsigned u = __builtin_bit_cast(unsigned, f);
    unsigned r = (u + 0x7FFFu + ((u >> 16) & 1u)) >> 16;
    return (unsigned short)r;
}

// ---------- W transpose: WtB[pid][col][k] = bf16(W[k][col]) ------------------
__global__ __launch_bounds__(256) void wtrans_kernel(
    const float* __restrict__ Wq, const float* __restrict__ Wk,
    const float* __restrict__ Wv, unsigned short* __restrict__ WtB)
{
    const int pid = blockIdx.z;
    const float* W = pid == 0 ? Wq : (pid == 1 ? Wk : Wv);
    unsigned short* T = WtB + (size_t)pid * DK * DM;
    const int k0 = blockIdx.x * 32, c0 = blockIdx.y * 32;
    __shared__ unsigned short tile[32][33];
    const int x = threadIdx.x & 31, y = threadIdx.x >> 5;   // 32 x 8
    #pragma unroll
    for (int i = 0; i < 32; i += 8)
        tile[y + i][x] = f2bf(W[(size_t)(k0 + y + i) * DK + c0 + x]);
    __syncthreads();
    #pragma unroll
    for (int i = 0; i < 32; i += 8)
        T[(size_t)(c0 + y + i) * DM + k0 + x] = tile[x][y + i];
}

// ---------- Projection: P = X @ W + b, bf16 out ------------------------------
// v4: 16-row blocks (768 total, 3/CU), 4 waves x 32 cols, double-buffered LDS
// X tile with ONE barrier per K-iter; next-iter global loads issued before
// compute so HBM latency hides under MFMA + L2 B-frag loads.
// q-projection pre-scaled by 1/sqrt(DK).
#define PBK 64
__global__ __launch_bounds__(256) void proj_kernel(
    const float* __restrict__ q, const float* __restrict__ k, const float* __restrict__ v,
    const float* __restrict__ bq, const float* __restrict__ bk, const float* __restrict__ bv,
    const unsigned short* __restrict__ WtB,
    unsigned short* __restrict__ qp, unsigned short* __restrict__ kp,
    unsigned short* __restrict__ vpF)
{
    const int pid = blockIdx.y;
    const float* X    = pid == 0 ? q  : (pid == 1 ? k  : v);
    const float* bias = pid == 0 ? bq : (pid == 1 ? bk : bv);
    unsigned short* out = pid == 0 ? qp : (pid == 1 ? kp : vpF);
    const unsigned short* Wt = WtB + (size_t)pid * DK * DM;
    const float oscale = pid == 0 ? 0.08838834764831843f : 1.0f;

    const int row0 = blockIdx.x * 16;
    const int tid  = threadIdx.x;
    const int lane = tid & 63;
    const int wave = tid >> 6;
    const int lw = lane & 15, lg = lane >> 4;
    const int wcol = wave * 32;

    __shared__ unsigned short Xs[2][16][PBK];   // 2 x 2 KB, XOR-swizzled granules

    f32x4 acc[2];
    acc[0] = f32x4{0.f, 0.f, 0.f, 0.f};
    acc[1] = f32x4{0.f, 0.f, 0.f, 0.f};

    // staging: threads 0..127, srow = t>>3 (16 rows), granule sg = t&7 (8 f32)
    const int srow = tid >> 3;
    const int sg   = tid & 7;
    const int sgs  = sg ^ (srow & 7);
    const bool stager = tid < 128;

    float4 pa, pb;
    if (stager) {
        const float* src = X + (size_t)(row0 + srow) * DM + sg * 8;
        pa = *reinterpret_cast<const float4*>(src);
        pb = *reinterpret_cast<const float4*>(src + 4);
        short8 xb;
        xb[0] = (short)f2bf(pa.x); xb[1] = (short)f2bf(pa.y);
        xb[2] = (short)f2bf(pa.z); xb[3] = (short)f2bf(pa.w);
        xb[4] = (short)f2bf(pb.x); xb[5] = (short)f2bf(pb.y);
        xb[6] = (short)f2bf(pb.z); xb[7] = (short)f2bf(pb.w);
        *reinterpret_cast<short8*>(&Xs[0][srow][sgs * 8]) = xb;
    }
    __syncthreads();

    for (int it = 0; it < DM / PBK; ++it) {
        const int buf = it & 1;
        // issue next chunk's global loads early (latency hides under compute)
        if (stager && it + 1 < DM / PBK) {
            const float* src = X + (size_t)(row0 + srow) * DM + (it + 1) * PBK + sg * 8;
            pa = *reinterpret_cast<const float4*>(src);
            pb = *reinterpret_cast<const float4*>(src + 4);
        }
        // compute current buffer
        const int k0 = it * PBK;
        #pragma unroll
        for (int kk = 0; kk < 2; kk++) {
            const int g = (kk * 4 + lg) ^ (lw & 7);
            short8 af = *reinterpret_cast<const short8*>(&Xs[buf][lw][g * 8]);
            #pragma unroll
            for (int f = 0; f < 2; f++) {
                const unsigned short* wp =
                    Wt + (size_t)(wcol + f * 16 + lw) * DM + k0 + kk * 32 + lg * 8;
                short8 bf = *reinterpret_cast<const short8*>(wp);
                acc[f] = __builtin_amdgcn_mfma_f32_16x16x32_bf16(af, bf, acc[f], 0, 0, 0);
            }
        }
        // write next buffer
        if (stager && it + 1 < DM / PBK) {
            short8 xb;
            xb[0] = (short)f2bf(pa.x); xb[1] = (short)f2bf(pa.y);
            xb[2] = (short)f2bf(pa.z); xb[3] = (short)f2bf(pa.w);
            xb[4] = (short)f2bf(pb.x); xb[5] = (short)f2bf(pb.y);
            xb[6] = (short)f2bf(pb.z); xb[7] = (short)f2bf(pb.w);
            *reinterpret_cast<short8*>(&Xs[buf ^ 1][srow][sgs * 8]) = xb;
        }
        __syncthreads();
    }

    const int orow = row0 + lg * 4;
    if (pid != 2) {
        #pragma unroll
        for (int f = 0; f < 2; f++) {
            int col = wcol + f * 16 + lw;
            float bb = bias[col];
            #pragma unroll
            for (int r = 0; r < 4; r++)
                out[(size_t)(orow + r) * DK + col] = f2bf((acc[f][r] + bb) * oscale);
        }
    } else {
        #pragma unroll
        for (int f = 0; f < 2; f++) {
            int col = wcol + f * 16 + lw;
            float bb = bias[col];
            #pragma unroll
            for (int r = 0; r < 4; r++) {
                int row = orow + r;
                out[(size_t)(row >> 5) * DK * 32 + (size_t)col * 32 + (row & 31)] =
                    f2bf(acc[f][r] + bb);
            }
        }
    }
}

// ---------- Attention phase 1: balanced split-K partials ---------------------
// Dense 1-D grid of 2176 units; unit u -> (q-tile i, 256-key block kb) via
// closed-form decode of u = 8a(a+1) + rr(a+1) + kb (a=i>>4, rr=i&15).
// 64-key inner tiles: 16 K-frag loads batched, both V slots prefetched during
// QK/softmax, causal mask only on the (wave-uniform) diagonal block.
__global__ __launch_bounds__(64, 2) void attn_part_kernel(
    const unsigned short* __restrict__ qp,
    const unsigned short* __restrict__ kp,
    const unsigned short* __restrict__ vpF,
    float* __restrict__ part_O, float* __restrict__ part_ml)
{
    const int u = blockIdx.x;
    int a = (int)(0.25f * (sqrtf(4.0f + 2.0f * (float)u) - 2.0f));
    while (8 * (a + 1) * (a + 2) <= u) ++a;
    while (8 * a * (a + 1) > u) --a;
    const int rem = u - 8 * a * (a + 1);
    const int rr2 = rem / (a + 1);
    const int kb = rem - rr2 * (a + 1);
    const int i  = a * 16 + rr2;

    const int lane = threadIdx.x;
    const int lw = lane & 15, lg = lane >> 4;
    const int q0 = i * 16;
    const int kstart = kb * 256;
    const int kend = min(kstart + 256, q0 + 16);
    const int nt = (kend - kstart + 63) >> 6;   // 64-key tiles
    const bool diag = (kb == a);

    __shared__ unsigned short Pl[16][72];   // +16B pad: ~2-way on b128 reads

    short8 qf[4];
    {
        const unsigned short* qb = qp + (size_t)(q0 + lw) * DK + lg * 8;
        #pragma unroll
        for (int t = 0; t < 4; t++)
            qf[t] = *reinterpret_cast<const short8*>(qb + t * 32);
    }

    f32x4 oacc[8];
    #pragma unroll
    for (int f = 0; f < 8; f++) oacc[f] = f32x4{0.f, 0.f, 0.f, 0.f};
    float m[4]    = {-1e30f, -1e30f, -1e30f, -1e30f};
    float lsum[4] = {0.f, 0.f, 0.f, 0.f};

    for (int t = 0; t < nt; ++t) {
        const int k0 = kstart + t * 64;

        // ---- QK^T over 64 keys: 16 batched K-frag loads, 4 indep MFMA chains
        short8 kf[4][4];   // [col-tile][k-chunk]
        const unsigned short* kbase = kp + (size_t)(k0 + lw) * DK + lg * 8;
        #pragma unroll
        for (int tt = 0; tt < 4; tt++)
            #pragma unroll
            for (int c = 0; c < 4; c++)
                kf[c][tt] = *reinterpret_cast<const short8*>(
                    kbase + (size_t)c * 16 * DK + tt * 32);
        f32x4 sc[4];
        #pragma unroll
        for (int c = 0; c < 4; c++) sc[c] = f32x4{0.f, 0.f, 0.f, 0.f};
        #pragma unroll
        for (int tt = 0; tt < 4; tt++)
            #pragma unroll
            for (int c = 0; c < 4; c++)
                sc[c] = __builtin_amdgcn_mfma_f32_16x16x32_bf16(qf[tt], kf[c][tt], sc[c], 0, 0, 0);

        // ---- V prefetch (both 32-key slots) — latency hides under softmax
        short8 vf[2][8];
        const unsigned short* vb = vpF + (size_t)(k0 >> 5) * DK * 32 + lg * 8;
        #pragma unroll
        for (int s = 0; s < 2; s++)
            #pragma unroll
            for (int f = 0; f < 8; f++)
                vf[s][f] = *reinterpret_cast<const short8*>(
                    vb + (size_t)s * DK * 32 + (size_t)(f * 16 + lw) * 32);

        // ---- causal mask: only the diagonal block (wave-uniform branch)
        if (diag) {
            #pragma unroll
            for (int c = 0; c < 4; c++) {
                int col = k0 + c * 16 + lw;
                #pragma unroll
                for (int r = 0; r < 4; r++)
                    if (col > q0 + lg * 4 + r) sc[c][r] = -1e30f;
            }
        }

        // ---- online softmax over 64 keys
        float mx[4], corr[4], rs[4];
        #pragma unroll
        for (int r = 0; r < 4; r++)
            mx[r] = fmaxf(fmaxf(sc[0][r], sc[1][r]), fmaxf(sc[2][r], sc[3][r]));
        #pragma unroll
        for (int off = 1; off < 16; off <<= 1) {
            #pragma unroll
            for (int r = 0; r < 4; r++)
                mx[r] = fmaxf(mx[r], __shfl_xor(mx[r], off));
        }
        #pragma unroll
        for (int r = 0; r < 4; r++) {
            float mn = fmaxf(m[r], mx[r]);
            corr[r] = __expf(m[r] - mn);
            m[r] = mn;
            float p0 = __expf(sc[0][r] - mn);
            float p1 = __expf(sc[1][r] - mn);
            float p2 = __expf(sc[2][r] - mn);
            float p3 = __expf(sc[3][r] - mn);
            rs[r] = (p0 + p1) + (p2 + p3);
            int row = lg * 4 + r;
            Pl[row][lw]      = f2bf(p0);
            Pl[row][16 + lw] = f2bf(p1);
            Pl[row][32 + lw] = f2bf(p2);
            Pl[row][48 + lw] = f2bf(p3);
        }
        #pragma unroll
        for (int off = 1; off < 16; off <<= 1) {
            #pragma unroll
            for (int r = 0; r < 4; r++)
                rs[r] += __shfl_xor(rs[r], off);
        }
        #pragma unroll
        for (int r = 0; r < 4; r++) lsum[r] = lsum[r] * corr[r] + rs[r];
        #pragma unroll
        for (int f = 0; f < 8; f++) {
            oacc[f][0] *= corr[0]; oacc[f][1] *= corr[1];
            oacc[f][2] *= corr[2]; oacc[f][3] *= corr[3];
        }

        // wave-local LDS fence: P writes -> P reads
        asm volatile("s_waitcnt lgkmcnt(0)" ::: "memory");

        // ---- PV over both 32-key slots (V already in registers)
        #pragma unroll
        for (int s = 0; s < 2; s++) {
            short8 pa = *reinterpret_cast<const short8*>(&Pl[lw][s * 32 + lg * 8]);
            #pragma unroll
            for (int f = 0; f < 8; f++)
                oacc[f] = __builtin_amdgcn_mfma_f32_16x16x32_bf16(pa, vf[s][f], oacc[f], 0, 0, 0);
        }
    }

    // ---- store partials
    float* po = part_O + (size_t)u * 2048;
    #pragma unroll
    for (int f = 0; f < 8; f++) {
        int col = f * 16 + lw;
        #pragma unroll
        for (int r = 0; r < 4; r++)
            po[(lg * 4 + r) * DK + col] = oacc[f][r];
    }
    if (lw == 0) {
        #pragma unroll
        for (int r = 0; r < 4; r++) {
            part_ml[(size_t)u * 32 + lg * 4 + r]      = m[r];
            part_ml[(size_t)u * 32 + 16 + lg * 4 + r] = lsum[r];
        }
    }
}

// ---------- Attention phase 2: LSE-weighted combine --------------------------
__global__ __launch_bounds__(128) void attn_comb_kernel(
    const float* __restrict__ part_O, const float* __restrict__ part_ml,
    float* __restrict__ out)
{
    const int i = blockIdx.x;
    const int nkb = (i + 16) >> 4;
    const int a = i >> 4, rr = i & 15;
    const int u0 = 8 * a * (a + 1) + rr * (a + 1);
    const int tid = threadIdx.x;

    __shared__ float wgt[16][16];   // [unit][row]
    __shared__ float invd[16];

    if (tid < 16) {
        float M = -1e30f;
        for (int u = 0; u < nkb; u++)
            M = fmaxf(M, part_ml[(size_t)(u0 + u) * 32 + tid]);
        float d = 0.f;
        for (int u = 0; u < nkb; u++) {
            float g = __expf(part_ml[(size_t)(u0 + u) * 32 + tid] - M);
            wgt[u][tid] = g;
            d += g * part_ml[(size_t)(u0 + u) * 32 + 16 + tid];
        }
        invd[tid] = 1.0f / d;
    }
    __syncthreads();

    #pragma unroll
    for (int j = 0; j < 16; j++) {
        int e = tid + 128 * j;              // 0..2047
        int r = e >> 7;
        float acc = 0.f;
        for (int u = 0; u < nkb; u++)
            acc += wgt[u][r] * part_O[(size_t)(u0 + u) * 2048 + e];
        out[(size_t)i * 2048 + e] = acc * invd[r];
    }
}

// ---------- Fallback: single-kernel split-K attn (qp pre-scaled) -------------
__global__ __launch_bounds__(512) void attn_fallback_kernel(
    const unsigned short* __restrict__ qp,
    const unsigned short* __restrict__ kp,
    const unsigned short* __restrict__ vpF,
    float* __restrict__ out)
{
    const int tid  = threadIdx.x;
    const int lane = tid & 63;
    const int wid  = tid >> 6;
    const int q0   = blockIdx.x * 16;
    const int lw = lane & 15, lg = lane >> 4;

    __shared__ unsigned short Pl[8][16][32];
    __shared__ float Ols[8][16][132];
    __shared__ float mls[8][16], lls[8][16];
    __shared__ float wgt[8][16], invd[16];

    short8 qf[4];
    {
        const unsigned short* qb = qp + (size_t)(q0 + lw) * DK + lg * 8;
        #pragma unroll
        for (int t = 0; t < 4; t++)
            qf[t] = *reinterpret_cast<const short8*>(qb + t * 32);
    }
    f32x4 oacc[8];
    #pragma unroll
    for (int i = 0; i < 8; i++) oacc[i] = f32x4{0.f, 0.f, 0.f, 0.f};
    float m[4]    = {-1e30f, -1e30f, -1e30f, -1e30f};
    float lsum[4] = {0.f, 0.f, 0.f, 0.f};
    const int nt = (q0 + 47) >> 5;

    for (int t = wid; t < nt; t += 8) {
        const int k0 = t * 32;
        f32x4 sc0 = f32x4{0.f, 0.f, 0.f, 0.f};
        f32x4 sc1 = f32x4{0.f, 0.f, 0.f, 0.f};
        {
            const unsigned short* kb0 = kp + (size_t)(k0 + lw) * DK + lg * 8;
            const unsigned short* kb1 = kb0 + 16 * DK;
            #pragma unroll
            for (int tt = 0; tt < 4; tt++) {
                short8 b0 = *reinterpret_cast<const short8*>(kb0 + tt * 32);
                short8 b1 = *reinterpret_cast<const short8*>(kb1 + tt * 32);
                sc0 = __builtin_amdgcn_mfma_f32_16x16x32_bf16(qf[tt], b0, sc0, 0, 0, 0);
                sc1 = __builtin_amdgcn_mfma_f32_16x16x32_bf16(qf[tt], b1, sc1, 0, 0, 0);
            }
        }
        float mx[4];
        #pragma unroll
        for (int r = 0; r < 4; r++) {
            int qg = q0 + lg * 4 + r;
            float s0 = sc0[r]; if (k0 + lw > qg)      s0 = -1e30f;
            float s1 = sc1[r]; if (k0 + 16 + lw > qg) s1 = -1e30f;
            sc0[r] = s0; sc1[r] = s1;
            mx[r] = fmaxf(s0, s1);
        }
        #pragma unroll
        for (int off = 1; off < 16; off <<= 1) {
            #pragma unroll
            for (int r = 0; r < 4; r++)
                mx[r] = fmaxf(mx[r], __shfl_xor(mx[r], off));
        }
        float corr[4], rs[4];
        #pragma unroll
        for (int r = 0; r < 4; r++) {
            float mn = fmaxf(m[r], mx[r]);
            corr[r] = __expf(m[r] - mn);
            m[r] = mn;
            float p0 = __expf(sc0[r] - mn);
            float p1 = __expf(sc1[r] - mn);
            rs[r] = p0 + p1;
            Pl[wid][lg * 4 + r][lw]      = f2bf(p0);
            Pl[wid][lg * 4 + r][16 + lw] = f2bf(p1);
        }
        #pragma unroll
        for (int off = 1; off < 16; off <<= 1) {
            #pragma unroll
            for (int r = 0; r < 4; r++)
                rs[r] += __shfl_xor(rs[r], off);
        }
        #pragma unroll
        for (int r = 0; r < 4; r++) lsum[r] = lsum[r] * corr[r] + rs[r];
        #pragma unroll
        for (int f = 0; f < 8; f++) {
            oacc[f][0] *= corr[0]; oacc[f][1] *= corr[1];
            oacc[f][2] *= corr[2]; oacc[f][3] *= corr[3];
        }
        asm volatile("s_waitcnt lgkmcnt(0)" ::: "memory");
        short8 pa = *reinterpret_cast<const short8*>(&Pl[wid][lw][lg * 8]);
        const unsigned short* vb = vpF + (size_t)(k0 >> 5) * DK * 32 + lg * 8;
        #pragma unroll
        for (int f = 0; f < 8; f++) {
            short8 bf = *reinterpret_cast<const short8*>(vb + (size_t)(f * 16 + lw) * 32);
            oacc[f] = __builtin_amdgcn_mfma_f32_16x16x32_bf16(pa, bf, oacc[f], 0, 0, 0);
        }
    }
    #pragma unroll
    for (int f = 0; f < 8; f++) {
        int col = f * 16 + lw;
        #pragma unroll
        for (int r = 0; r < 4; r++)
            Ols[wid][lg * 4 + r][col] = oacc[f][r];
    }
    if (lw == 0) {
        #pragma unroll
        for (int r = 0; r < 4; r++) {
            mls[wid][lg * 4 + r] = m[r];
            lls[wid][lg * 4 + r] = lsum[r];
        }
    }
    __syncthreads();
    if (tid < 16) {
        float M = mls[0][tid];
        #pragma unroll
        for (int w2 = 1; w2 < 8; w2++) M = fmaxf(M, mls[w2][tid]);
        float d = 0.f;
        #pragma unroll
        for (int w2 = 0; w2 < 8; w2++) {
            float g = __expf(mls[w2][tid] - M);
            wgt[w2][tid] = g;
            d += g * lls[w2][tid];
        }
        invd[tid] = 1.0f / d;
    }
    __syncthreads();
    #pragma unroll
    for (int j = 0; j < 4; j++) {
        int e = tid + 512 * j;
        int r = e >> 7, c = e & 127;
        float num = 0.f;
        #pragma unroll
        for (int w2 = 0; w2 < 8; w2++) num += wgt[w2][r] * Ols[w2][r][c];
        out[(size_t)(q0 + r) * DK + c] = num * invd[r];
    }
}

extern "C" void kernel_launch(void* const* d_in, const int* in_sizes, int n_in,
                              void* d_out, int out_size, void* d_ws, size_t ws_size,
                              hipStream_t stream) {
    const float* q  = (const float*)d_in[0];
    const float* k  = (const float*)d_in[1];
    const float* v  = (const float*)d_in[2];
    const float* Wq = (const float*)d_in[3];
    const float* bq = (const float*)d_in[4];
    const float* Wk = (const float*)d_in[5];
    const float* bk = (const float*)d_in[6];
    const float* Wv = (const float*)d_in[7];
    const float* bv = (const float*)d_in[8];

    unsigned short* qp  = (unsigned short*)d_ws;
    unsigned short* kp  = qp + (size_t)S * DK;
    unsigned short* vpF = kp + (size_t)S * DK;
    unsigned short* WtB = vpF + (size_t)S * DK;          // [3][128][1024] bf16
    float* part_O  = (float*)(WtB + (size_t)3 * DK * DM); // [2176][16][128] f32
    float* part_ml = part_O + (size_t)2176 * 2048;        // [2176][32] f32

    const size_t ws_need = ((size_t)3 * S * DK + (size_t)3 * DK * DM) * 2 +
                           ((size_t)2176 * 2048 + (size_t)2176 * 32) * 4;

    dim3 gt(DM / 32, DK / 32, 3);
    wtrans_kernel<<<gt, 256, 0, stream>>>(Wq, Wk, Wv, WtB);

    dim3 gp(S / 16, 3);
    proj_kernel<<<gp, 256, 0, stream>>>(q, k, v, bq, bk, bv, WtB, qp, kp, vpF);

    if (ws_size >= ws_need) {
        attn_part_kernel<<<2176, 64, 0, stream>>>(qp, kp, vpF, part_O, part_ml);
        attn_comb_kernel<<<S / 16, 128, 0, stream>>>(part_O, part_ml, (float*)d_out);
    } else {
        attn_fallback_kernel<<<S / 16, 512, 0, stream>>>(qp, kp, vpF, (float*)d_out);
    }
}

// Round 9
// 162.361 us; speedup vs baseline: 1.3384x; 1.1766x over previous
//
#include <hip/hip_runtime.h>
#include <hip/hip_bf16.h>
#include <math.h>

#define S   4096
#define DM  1024
#define DK  128

typedef __attribute__((ext_vector_type(8))) short short8;
typedef __attribute__((ext_vector_type(4))) float f32x4;

static __device__ __forceinline__ unsigned short f2bf(float f) {
    unsigned u = __builtin_bit_cast(unsigned, f);
    unsigned r = (u + 0x7FFFu + ((u >> 16) & 1u)) >> 16;
    return (unsigned short)r;
}

// ---------- W transpose: WtB[pid][col][k] = bf16(W[k][col]) ------------------
__global__ __launch_bounds__(256) void wtrans_kernel(
    const float* __restrict__ Wq, const float* __restrict__ Wk,
    const float* __restrict__ Wv, unsigned short* __restrict__ WtB)
{
    const int pid = blockIdx.z;
    const float* W = pid == 0 ? Wq : (pid == 1 ? Wk : Wv);
    unsigned short* T = WtB + (size_t)pid * DK * DM;
    const int k0 = blockIdx.x * 32, c0 = blockIdx.y * 32;
    __shared__ unsigned short tile[32][33];
    const int x = threadIdx.x & 31, y = threadIdx.x >> 5;   // 32 x 8
    #pragma unroll
    for (int i = 0; i < 32; i += 8)
        tile[y + i][x] = f2bf(W[(size_t)(k0 + y + i) * DK + c0 + x]);
    __syncthreads();
    #pragma unroll
    for (int i = 0; i < 32; i += 8)
        T[(size_t)(c0 + y + i) * DM + k0 + x] = tile[x][y + i];
}

// ---------- Projection: P = X @ W + b, bf16 out ------------------------------
// 16-row blocks (768 total, 3/CU), 4 waves x 32 cols, double-buffered LDS
// X tile with ONE barrier per K-iter; next-iter global loads issued before
// compute so HBM latency hides under MFMA + L2 B-frag loads.
// q-projection pre-scaled by 1/sqrt(DK).
#define PBK 64
__global__ __launch_bounds__(256) void proj_kernel(
    const float* __restrict__ q, const float* __restrict__ k, const float* __restrict__ v,
    const float* __restrict__ bq, const float* __restrict__ bk, const float* __restrict__ bv,
    const unsigned short* __restrict__ WtB,
    unsigned short* __restrict__ qp, unsigned short* __restrict__ kp,
    unsigned short* __restrict__ vpF)
{
    const int pid = blockIdx.y;
    const float* X    = pid == 0 ? q  : (pid == 1 ? k  : v);
    const float* bias = pid == 0 ? bq : (pid == 1 ? bk : bv);
    unsigned short* out = pid == 0 ? qp : (pid == 1 ? kp : vpF);
    const unsigned short* Wt = WtB + (size_t)pid * DK * DM;
    const float oscale = pid == 0 ? 0.08838834764831843f : 1.0f;

    const int row0 = blockIdx.x * 16;
    const int tid  = threadIdx.x;
    const int lane = tid & 63;
    const int wave = tid >> 6;
    const int lw = lane & 15, lg = lane >> 4;
    const int wcol = wave * 32;

    __shared__ unsigned short Xs[2][16][PBK];   // 2 x 2 KB, XOR-swizzled granules

    f32x4 acc[2];
    acc[0] = f32x4{0.f, 0.f, 0.f, 0.f};
    acc[1] = f32x4{0.f, 0.f, 0.f, 0.f};

    // staging: threads 0..127, srow = t>>3 (16 rows), granule sg = t&7 (8 f32)
    const int srow = tid >> 3;
    const int sg   = tid & 7;
    const int sgs  = sg ^ (srow & 7);
    const bool stager = tid < 128;

    float4 pa, pb;
    if (stager) {
        const float* src = X + (size_t)(row0 + srow) * DM + sg * 8;
        pa = *reinterpret_cast<const float4*>(src);
        pb = *reinterpret_cast<const float4*>(src + 4);
        short8 xb;
        xb[0] = (short)f2bf(pa.x); xb[1] = (short)f2bf(pa.y);
        xb[2] = (short)f2bf(pa.z); xb[3] = (short)f2bf(pa.w);
        xb[4] = (short)f2bf(pb.x); xb[5] = (short)f2bf(pb.y);
        xb[6] = (short)f2bf(pb.z); xb[7] = (short)f2bf(pb.w);
        *reinterpret_cast<short8*>(&Xs[0][srow][sgs * 8]) = xb;
    }
    __syncthreads();

    for (int it = 0; it < DM / PBK; ++it) {
        const int buf = it & 1;
        // issue next chunk's global loads early (latency hides under compute)
        if (stager && it + 1 < DM / PBK) {
            const float* src = X + (size_t)(row0 + srow) * DM + (it + 1) * PBK + sg * 8;
            pa = *reinterpret_cast<const float4*>(src);
            pb = *reinterpret_cast<const float4*>(src + 4);
        }
        // compute current buffer
        const int k0 = it * PBK;
        #pragma unroll
        for (int kk = 0; kk < 2; kk++) {
            const int g = (kk * 4 + lg) ^ (lw & 7);
            short8 af = *reinterpret_cast<const short8*>(&Xs[buf][lw][g * 8]);
            #pragma unroll
            for (int f = 0; f < 2; f++) {
                const unsigned short* wp =
                    Wt + (size_t)(wcol + f * 16 + lw) * DM + k0 + kk * 32 + lg * 8;
                short8 bf = *reinterpret_cast<const short8*>(wp);
                acc[f] = __builtin_amdgcn_mfma_f32_16x16x32_bf16(af, bf, acc[f], 0, 0, 0);
            }
        }
        // write next buffer
        if (stager && it + 1 < DM / PBK) {
            short8 xb;
            xb[0] = (short)f2bf(pa.x); xb[1] = (short)f2bf(pa.y);
            xb[2] = (short)f2bf(pa.z); xb[3] = (short)f2bf(pa.w);
            xb[4] = (short)f2bf(pb.x); xb[5] = (short)f2bf(pb.y);
            xb[6] = (short)f2bf(pb.z); xb[7] = (short)f2bf(pb.w);
            *reinterpret_cast<short8*>(&Xs[buf ^ 1][srow][sgs * 8]) = xb;
        }
        __syncthreads();
    }

    const int orow = row0 + lg * 4;
    if (pid != 2) {
        #pragma unroll
        for (int f = 0; f < 2; f++) {
            int col = wcol + f * 16 + lw;
            float bb = bias[col];
            #pragma unroll
            for (int r = 0; r < 4; r++)
                out[(size_t)(orow + r) * DK + col] = f2bf((acc[f][r] + bb) * oscale);
        }
    } else {
        #pragma unroll
        for (int f = 0; f < 2; f++) {
            int col = wcol + f * 16 + lw;
            float bb = bias[col];
            #pragma unroll
            for (int r = 0; r < 4; r++) {
                int row = orow + r;
                out[(size_t)(row >> 5) * DK * 32 + (size_t)col * 32 + (row & 31)] =
                    f2bf(acc[f][r] + bb);
            }
        }
    }
}

// ---------- Attention phase 1: balanced split-K partials ---------------------
// Dense 1-D grid of 2176 units; unit u -> (q-tile i, 256-key block kb) via
// closed-form decode of u = 8a(a+1) + rr(a+1) + kb (a=i>>4, rr=i&15).
// 64-key inner tiles: 16 K-frag loads batched, both V slots prefetched during
// QK/softmax, causal mask only on the (wave-uniform) diagonal block.
__global__ __launch_bounds__(64, 2) void attn_part_kernel(
    const unsigned short* __restrict__ qp,
    const unsigned short* __restrict__ kp,
    const unsigned short* __restrict__ vpF,
    float* __restrict__ part_O, float* __restrict__ part_ml)
{
    const int u = blockIdx.x;
    int a = (int)(0.25f * (sqrtf(4.0f + 2.0f * (float)u) - 2.0f));
    while (8 * (a + 1) * (a + 2) <= u) ++a;
    while (8 * a * (a + 1) > u) --a;
    const int rem = u - 8 * a * (a + 1);
    const int rr2 = rem / (a + 1);
    const int kb = rem - rr2 * (a + 1);
    const int i  = a * 16 + rr2;

    const int lane = threadIdx.x;
    const int lw = lane & 15, lg = lane >> 4;
    const int q0 = i * 16;
    const int kstart = kb * 256;
    const int kend = min(kstart + 256, q0 + 16);
    const int nt = (kend - kstart + 63) >> 6;   // 64-key tiles
    const bool diag = (kb == a);

    __shared__ unsigned short Pl[16][72];   // +16B pad: ~2-way on b128 reads

    short8 qf[4];
    {
        const unsigned short* qb = qp + (size_t)(q0 + lw) * DK + lg * 8;
        #pragma unroll
        for (int t = 0; t < 4; t++)
            qf[t] = *reinterpret_cast<const short8*>(qb + t * 32);
    }

    f32x4 oacc[8];
    #pragma unroll
    for (int f = 0; f < 8; f++) oacc[f] = f32x4{0.f, 0.f, 0.f, 0.f};
    float m[4]    = {-1e30f, -1e30f, -1e30f, -1e30f};
    float lsum[4] = {0.f, 0.f, 0.f, 0.f};

    for (int t = 0; t < nt; ++t) {
        const int k0 = kstart + t * 64;

        // ---- QK^T over 64 keys: 16 batched K-frag loads, 4 indep MFMA chains
        short8 kf[4][4];   // [col-tile][k-chunk]
        const unsigned short* kbase = kp + (size_t)(k0 + lw) * DK + lg * 8;
        #pragma unroll
        for (int tt = 0; tt < 4; tt++)
            #pragma unroll
            for (int c = 0; c < 4; c++)
                kf[c][tt] = *reinterpret_cast<const short8*>(
                    kbase + (size_t)c * 16 * DK + tt * 32);
        f32x4 sc[4];
        #pragma unroll
        for (int c = 0; c < 4; c++) sc[c] = f32x4{0.f, 0.f, 0.f, 0.f};
        #pragma unroll
        for (int tt = 0; tt < 4; tt++)
            #pragma unroll
            for (int c = 0; c < 4; c++)
                sc[c] = __builtin_amdgcn_mfma_f32_16x16x32_bf16(qf[tt], kf[c][tt], sc[c], 0, 0, 0);

        // ---- V prefetch (both 32-key slots) — latency hides under softmax
        short8 vf[2][8];
        const unsigned short* vb = vpF + (size_t)(k0 >> 5) * DK * 32 + lg * 8;
        #pragma unroll
        for (int s = 0; s < 2; s++)
            #pragma unroll
            for (int f = 0; f < 8; f++)
                vf[s][f] = *reinterpret_cast<const short8*>(
                    vb + (size_t)s * DK * 32 + (size_t)(f * 16 + lw) * 32);

        // ---- causal mask: only the diagonal block (wave-uniform branch)
        if (diag) {
            #pragma unroll
            for (int c = 0; c < 4; c++) {
                int col = k0 + c * 16 + lw;
                #pragma unroll
                for (int r = 0; r < 4; r++)
                    if (col > q0 + lg * 4 + r) sc[c][r] = -1e30f;
            }
        }

        // ---- online softmax over 64 keys
        float mx[4], corr[4], rs[4];
        #pragma unroll
        for (int r = 0; r < 4; r++)
            mx[r] = fmaxf(fmaxf(sc[0][r], sc[1][r]), fmaxf(sc[2][r], sc[3][r]));
        #pragma unroll
        for (int off = 1; off < 16; off <<= 1) {
            #pragma unroll
            for (int r = 0; r < 4; r++)
                mx[r] = fmaxf(mx[r], __shfl_xor(mx[r], off));
        }
        #pragma unroll
        for (int r = 0; r < 4; r++) {
            float mn = fmaxf(m[r], mx[r]);
            corr[r] = __expf(m[r] - mn);
            m[r] = mn;
            float p0 = __expf(sc[0][r] - mn);
            float p1 = __expf(sc[1][r] - mn);
            float p2 = __expf(sc[2][r] - mn);
            float p3 = __expf(sc[3][r] - mn);
            rs[r] = (p0 + p1) + (p2 + p3);
            int row = lg * 4 + r;
            Pl[row][lw]      = f2bf(p0);
            Pl[row][16 + lw] = f2bf(p1);
            Pl[row][32 + lw] = f2bf(p2);
            Pl[row][48 + lw] = f2bf(p3);
        }
        #pragma unroll
        for (int off = 1; off < 16; off <<= 1) {
            #pragma unroll
            for (int r = 0; r < 4; r++)
                rs[r] += __shfl_xor(rs[r], off);
        }
        #pragma unroll
        for (int r = 0; r < 4; r++) lsum[r] = lsum[r] * corr[r] + rs[r];
        #pragma unroll
        for (int f = 0; f < 8; f++) {
            oacc[f][0] *= corr[0]; oacc[f][1] *= corr[1];
            oacc[f][2] *= corr[2]; oacc[f][3] *= corr[3];
        }

        // wave-local LDS fence: P writes -> P reads
        asm volatile("s_waitcnt lgkmcnt(0)" ::: "memory");

        // ---- PV over both 32-key slots (V already in registers)
        #pragma unroll
        for (int s = 0; s < 2; s++) {
            short8 pa = *reinterpret_cast<const short8*>(&Pl[lw][s * 32 + lg * 8]);
            #pragma unroll
            for (int f = 0; f < 8; f++)
                oacc[f] = __builtin_amdgcn_mfma_f32_16x16x32_bf16(pa, vf[s][f], oacc[f], 0, 0, 0);
        }
    }

    // ---- store partials
    float* po = part_O + (size_t)u * 2048;
    #pragma unroll
    for (int f = 0; f < 8; f++) {
        int col = f * 16 + lw;
        #pragma unroll
        for (int r = 0; r < 4; r++)
            po[(lg * 4 + r) * DK + col] = oacc[f][r];
    }
    if (lw == 0) {
        #pragma unroll
        for (int r = 0; r < 4; r++) {
            part_ml[(size_t)u * 32 + lg * 4 + r]      = m[r];
            part_ml[(size_t)u * 32 + 16 + lg * 4 + r] = lsum[r];
        }
    }
}

// ---------- Attention phase 2: online LSE merge, 1 thread / output element ---
// 524288 threads (2048 blocks x 256): full TLP latency hiding. Single-pass
// online merge (running M, denom, acc) — algebraically identical to the
// two-pass LSE-weighted combine.
__global__ __launch_bounds__(256) void attn_comb_kernel(
    const float* __restrict__ part_O, const float* __restrict__ part_ml,
    float* __restrict__ out)
{
    const int eg = blockIdx.x * 256 + threadIdx.x;   // 0..524287
    const int i  = eg >> 11;                         // q-tile
    const int e  = eg & 2047;
    const int r  = e >> 7;
    const int a  = i >> 4, rr = i & 15;
    const int nkb = a + 1;
    const int u0  = 8 * a * (a + 1) + rr * (a + 1);

    float M = -1e30f, d = 0.f, acc = 0.f;
    for (int u = 0; u < nkb; u++) {
        const float* mlp = part_ml + (size_t)(u0 + u) * 32;
        float mu = mlp[r];
        float lu = mlp[16 + r];
        float Ou = part_O[(size_t)(u0 + u) * 2048 + e];
        float Mn = fmaxf(M, mu);
        float s_old = __expf(M - Mn);
        float s_new = __expf(mu - Mn);
        acc = acc * s_old + s_new * Ou;
        d   = d   * s_old + s_new * lu;
        M = Mn;
    }
    out[eg] = acc / d;
}

// ---------- Fallback: single-kernel split-K attn (qp pre-scaled) -------------
__global__ __launch_bounds__(512) void attn_fallback_kernel(
    const unsigned short* __restrict__ qp,
    const unsigned short* __restrict__ kp,
    const unsigned short* __restrict__ vpF,
    float* __restrict__ out)
{
    const int tid  = threadIdx.x;
    const int lane = tid & 63;
    const int wid  = tid >> 6;
    const int q0   = blockIdx.x * 16;
    const int lw = lane & 15, lg = lane >> 4;

    __shared__ unsigned short Pl[8][16][32];
    __shared__ float Ols[8][16][132];
    __shared__ float mls[8][16], lls[8][16];
    __shared__ float wgt[8][16], invd[16];

    short8 qf[4];
    {
        const unsigned short* qb = qp + (size_t)(q0 + lw) * DK + lg * 8;
        #pragma unroll
        for (int t = 0; t < 4; t++)
            qf[t] = *reinterpret_cast<const short8*>(qb + t * 32);
    }
    f32x4 oacc[8];
    #pragma unroll
    for (int i = 0; i < 8; i++) oacc[i] = f32x4{0.f, 0.f, 0.f, 0.f};
    float m[4]    = {-1e30f, -1e30f, -1e30f, -1e30f};
    float lsum[4] = {0.f, 0.f, 0.f, 0.f};
    const int nt = (q0 + 47) >> 5;

    for (int t = wid; t < nt; t += 8) {
        const int k0 = t * 32;
        f32x4 sc0 = f32x4{0.f, 0.f, 0.f, 0.f};
        f32x4 sc1 = f32x4{0.f, 0.f, 0.f, 0.f};
        {
            const unsigned short* kb0 = kp + (size_t)(k0 + lw) * DK + lg * 8;
            const unsigned short* kb1 = kb0 + 16 * DK;
            #pragma unroll
            for (int tt = 0; tt < 4; tt++) {
                short8 b0 = *reinterpret_cast<const short8*>(kb0 + tt * 32);
                short8 b1 = *reinterpret_cast<const short8*>(kb1 + tt * 32);
                sc0 = __builtin_amdgcn_mfma_f32_16x16x32_bf16(qf[tt], b0, sc0, 0, 0, 0);
                sc1 = __builtin_amdgcn_mfma_f32_16x16x32_bf16(qf[tt], b1, sc1, 0, 0, 0);
            }
        }
        float mx[4];
        #pragma unroll
        for (int r = 0; r < 4; r++) {
            int qg = q0 + lg * 4 + r;
            float s0 = sc0[r]; if (k0 + lw > qg)      s0 = -1e30f;
            float s1 = sc1[r]; if (k0 + 16 + lw > qg) s1 = -1e30f;
            sc0[r] = s0; sc1[r] = s1;
            mx[r] = fmaxf(s0, s1);
        }
        #pragma unroll
        for (int off = 1; off < 16; off <<= 1) {
            #pragma unroll
            for (int r = 0; r < 4; r++)
                mx[r] = fmaxf(mx[r], __shfl_xor(mx[r], off));
        }
        float corr[4], rs[4];
        #pragma unroll
        for (int r = 0; r < 4; r++) {
            float mn = fmaxf(m[r], mx[r]);
            corr[r] = __expf(m[r] - mn);
            m[r] = mn;
            float p0 = __expf(sc0[r] - mn);
            float p1 = __expf(sc1[r] - mn);
            rs[r] = p0 + p1;
            Pl[wid][lg * 4 + r][lw]      = f2bf(p0);
            Pl[wid][lg * 4 + r][16 + lw] = f2bf(p1);
        }
        #pragma unroll
        for (int off = 1; off < 16; off <<= 1) {
            #pragma unroll
            for (int r = 0; r < 4; r++)
                rs[r] += __shfl_xor(rs[r], off);
        }
        #pragma unroll
        for (int r = 0; r < 4; r++) lsum[r] = lsum[r] * corr[r] + rs[r];
        #pragma unroll
        for (int f = 0; f < 8; f++) {
            oacc[f][0] *= corr[0]; oacc[f][1] *= corr[1];
            oacc[f][2] *= corr[2]; oacc[f][3] *= corr[3];
        }
        asm volatile("s_waitcnt lgkmcnt(0)" ::: "memory");
        short8 pa = *reinterpret_cast<const short8*>(&Pl[wid][lw][lg * 8]);
        const unsigned short* vb = vpF + (size_t)(k0 >> 5) * DK * 32 + lg * 8;
        #pragma unroll
        for (int f = 0; f < 8; f++) {
            short8 bf = *reinterpret_cast<const short8*>(vb + (size_t)(f * 16 + lw) * 32);
            oacc[f] = __builtin_amdgcn_mfma_f32_16x16x32_bf16(pa, bf, oacc[f], 0, 0, 0);
        }
    }
    #pragma unroll
    for (int f = 0; f < 8; f++) {
        int col = f * 16 + lw;
        #pragma unroll
        for (int r = 0; r < 4; r++)
            Ols[wid][lg * 4 + r][col] = oacc[f][r];
    }
    if (lw == 0) {
        #pragma unroll
        for (int r = 0; r < 4; r++) {
            mls[wid][lg * 4 + r] = m[r];
            lls[wid][lg * 4 + r] = lsum[r];
        }
    }
    __syncthreads();
    if (tid < 16) {
        float M = mls[0][tid];
        #pragma unroll
        for (int w2 = 1; w2 < 8; w2++) M = fmaxf(M, mls[w2][tid]);
        float d = 0.f;
        #pragma unroll
        for (int w2 = 0; w2 < 8; w2++) {
            float g = __expf(mls[w2][tid] - M);
            wgt[w2][tid] = g;
            d += g * lls[w2][tid];
        }
        invd[tid] = 1.0f / d;
    }
    __syncthreads();
    #pragma unroll
    for (int j = 0; j < 4; j++) {
        int e = tid + 512 * j;
        int r = e >> 7, c = e & 127;
        float num = 0.f;
        #pragma unroll
        for (int w2 = 0; w2 < 8; w2++) num += wgt[w2][r] * Ols[w2][r][c];
        out[(size_t)(q0 + r) * DK + c] = num * invd[r];
    }
}

extern "C" void kernel_launch(void* const* d_in, const int* in_sizes, int n_in,
                              void* d_out, int out_size, void* d_ws, size_t ws_size,
                              hipStream_t stream) {
    const float* q  = (const float*)d_in[0];
    const float* k  = (const float*)d_in[1];
    const float* v  = (const float*)d_in[2];
    const float* Wq = (const float*)d_in[3];
    const float* bq = (const float*)d_in[4];
    const float* Wk = (const float*)d_in[5];
    const float* bk = (const float*)d_in[6];
    const float* Wv = (const float*)d_in[7];
    const float* bv = (const float*)d_in[8];

    unsigned short* qp  = (unsigned short*)d_ws;
    unsigned short* kp  = qp + (size_t)S * DK;
    unsigned short* vpF = kp + (size_t)S * DK;
    unsigned short* WtB = vpF + (size_t)S * DK;          // [3][128][1024] bf16
    float* part_O  = (float*)(WtB + (size_t)3 * DK * DM); // [2176][16][128] f32
    float* part_ml = part_O + (size_t)2176 * 2048;        // [2176][32] f32

    const size_t ws_need = ((size_t)3 * S * DK + (size_t)3 * DK * DM) * 2 +
                           ((size_t)2176 * 2048 + (size_t)2176 * 32) * 4;

    dim3 gt(DM / 32, DK / 32, 3);
    wtrans_kernel<<<gt, 256, 0, stream>>>(Wq, Wk, Wv, WtB);

    dim3 gp(S / 16, 3);
    proj_kernel<<<gp, 256, 0, stream>>>(q, k, v, bq, bk, bv, WtB, qp, kp, vpF);

    if (ws_size >= ws_need) {
        attn_part_kernel<<<2176, 64, 0, stream>>>(qp, kp, vpF, part_O, part_ml);
        attn_comb_kernel<<<(S * DK) / 256, 256, 0, stream>>>(part_O, part_ml, (float*)d_out);
    } else {
        attn_fallback_kernel<<<S / 16, 512, 0, stream>>>(qp, kp, vpF, (float*)d_out);
    }
}